// Round 1
// baseline (506.489 us; speedup 1.0000x reference)
//
#include <hip/hip_runtime.h>

// Problem constants (fixed by reference setup_inputs)
#define BATCH 16
#define HH 64
#define WW 64
#define CC 1024
#define GG 32
#define CG 32          // channels per group
#define TH 8           // tile rows per block
#define TW 16          // tile cols per block
#define EPS 1e-3f
#define ALPHA 0.3f

// LDS: x halo tile 10*18*32 floats = 23 KB, reused for y tile 128*36 floats (18 KB)
#define XS_FLOATS ((TH + 2) * (TW + 2) * CG)   // 5760
#define YS_STRIDE 36                            // padded row stride for y[pixel][c]

__global__ __launch_bounds__(256, 4)
void fused_dw_pw_bn_lrelu(const float* __restrict__ x,
                          const float* __restrict__ dwk,   // (3,3,1,C)
                          const float* __restrict__ pwk,   // (G,Cg,Cg)
                          const float* __restrict__ gamma,
                          const float* __restrict__ beta,
                          const float* __restrict__ mmean,
                          const float* __restrict__ mvar,
                          float* __restrict__ out) {
    __shared__ float smem[XS_FLOATS];

    const int t = threadIdx.x;
    const int tilesW = WW / TW;                 // 4
    const int tile  = blockIdx.x;               // 0..31
    const int tw0   = (tile % tilesW) * TW;
    const int th0   = (tile / tilesW) * TH;
    const int g     = blockIdx.y;               // 0..31
    const int b     = blockIdx.z;               // 0..15
    const int cbase = g * CG;

    // ---------- phase 0: global -> LDS, x halo tile xs[r][col][c] ----------
    // 10*18 pixel positions * 8 float4 each = 1440 float4 loads
    for (int i = t; i < (TH + 2) * (TW + 2) * 8; i += 256) {
        int q   = i & 7;                        // float4 index within 32 channels
        int pp  = i >> 3;                       // halo pixel position 0..179
        int r   = pp / (TW + 2);
        int col = pp % (TW + 2);
        int gh  = th0 - 1 + r;
        int gw  = tw0 - 1 + col;
        float4 v = make_float4(0.f, 0.f, 0.f, 0.f);
        if (gh >= 0 && gh < HH && gw >= 0 && gw < WW) {
            v = *(const float4*)(x + ((size_t)(b * HH + gh) * WW + gw) * CC + cbase + q * 4);
        }
        *(float4*)(smem + (size_t)pp * CG + q * 4) = v;
    }

    // ---------- depthwise taps for this thread's channel quad ----------
    const int c4    = (t & 7) * 4;              // channel quad base within group
    const int pslot = t >> 3;                   // 0..31 pixel slot
    float4 k9[9];
    #pragma unroll
    for (int j = 0; j < 9; ++j)
        k9[j] = *(const float4*)(dwk + j * CC + cbase + c4);

    __syncthreads();

    // ---------- phase 1: depthwise conv into registers ----------
    float4 yv[4];
    #pragma unroll
    for (int i = 0; i < 4; ++i) {
        int p  = pslot + i * 32;                // pixel 0..127
        int pr = p / TW, pc = p % TW;
        float4 acc = make_float4(0.f, 0.f, 0.f, 0.f);
        #pragma unroll
        for (int dy = 0; dy < 3; ++dy) {
            #pragma unroll
            for (int dx = 0; dx < 3; ++dx) {
                float4 xv = *(const float4*)(smem + ((pr + dy) * (TW + 2) + (pc + dx)) * CG + c4);
                float4 kk = k9[dy * 3 + dx];
                acc.x += xv.x * kk.x;
                acc.y += xv.y * kk.y;
                acc.z += xv.z * kk.z;
                acc.w += xv.w * kk.w;
            }
        }
        yv[i] = acc;
    }

    __syncthreads();    // all xs reads done; safe to overwrite smem with y

    #pragma unroll
    for (int i = 0; i < 4; ++i) {
        int p = pslot + i * 32;
        *(float4*)(smem + p * YS_STRIDE + c4) = yv[i];
    }

    // ---------- pointwise weights + BN constants for output channel d ----------
    const int d   = t & (CG - 1);               // 0..31
    const int ps2 = t >> 5;                     // 0..7
    float wreg[CG];
    #pragma unroll
    for (int c = 0; c < CG; ++c)
        wreg[c] = pwk[(g * CG + c) * CG + d];
    float sc = gamma[cbase + d] * rsqrtf(mvar[cbase + d] + EPS);
    float bi = beta[cbase + d] - mmean[cbase + d] * sc;

    __syncthreads();    // y tile visible

    // ---------- phase 2: pointwise + BN + LeakyReLU + store ----------
    for (int i = 0; i < 16; ++i) {
        int p = ps2 + i * 8;                    // pixel 0..127
        float acc = 0.f;
        #pragma unroll
        for (int cq = 0; cq < 8; ++cq) {
            float4 y4 = *(const float4*)(smem + p * YS_STRIDE + cq * 4);  // wave-broadcast
            acc += y4.x * wreg[cq * 4 + 0] + y4.y * wreg[cq * 4 + 1]
                 + y4.z * wreg[cq * 4 + 2] + y4.w * wreg[cq * 4 + 3];
        }
        float z = acc * sc + bi;
        z = (z >= 0.f) ? z : ALPHA * z;
        int pr = p / TW, pc = p % TW;
        out[((size_t)(b * HH + (th0 + pr)) * WW + (tw0 + pc)) * CC + cbase + d] = z;
    }
}

extern "C" void kernel_launch(void* const* d_in, const int* in_sizes, int n_in,
                              void* d_out, int out_size, void* d_ws, size_t ws_size,
                              hipStream_t stream) {
    const float* x     = (const float*)d_in[0];
    const float* dwk   = (const float*)d_in[1];
    const float* pwk   = (const float*)d_in[2];
    const float* gamma = (const float*)d_in[3];
    const float* beta  = (const float*)d_in[4];
    const float* mmean = (const float*)d_in[5];
    const float* mvar  = (const float*)d_in[6];
    float* out = (float*)d_out;

    dim3 grid((HH / TH) * (WW / TW), GG, BATCH);  // (32, 32, 16)
    dim3 block(256);
    hipLaunchKernelGGL(fused_dw_pw_bn_lrelu, grid, block, 0, stream,
                       x, dwk, pwk, gamma, beta, mmean, mvar, out);
}